// Round 2
// 4167.056 us; speedup vs baseline: 2.4256x; 2.4256x over previous
//
#include <hip/hip_runtime.h>
#include <stdint.h>

// ---------------- problem constants ----------------
#define TT    512
#define HH    512
#define EE    128
#define G7    (7*HH)    // 3584
#define H6    (6*HH)    // 3072
#define TP1   (TT+1)    // 513

// ---------------- scan decomposition ----------------
// grid 64 = 4 batch-groups x 16 i-groups. Block = 1024 threads (16 waves).
// Each wave owns one 16-col MFMA tile; block covers 7 gates x 32 hidden idx (224 cols of 256).
#define BW 16
#define II 32
#define NIG 16
#define NCOL 224
#define HLDS 520        // u16 row stride: 1040 B = 16*65, 16B-aligned rows

typedef float f32x4 __attribute__((ext_vector_type(4)));
typedef short short8 __attribute__((ext_vector_type(8)));

__device__ __forceinline__ float bf2f(unsigned short u){
  union { unsigned u32; float f; } v; v.u32 = ((unsigned)u) << 16; return v.f;
}
__device__ __forceinline__ unsigned short f2bf(float f){
  union { float f; unsigned u; } v; v.f = f;
  unsigned u = v.u;
  u += 0x7FFFu + ((u >> 16) & 1u);   // RNE
  return (unsigned short)(u >> 16);
}
__device__ __forceinline__ float sigmoidf_(float x){ return 1.0f/(1.0f+__expf(-x)); }
__device__ __forceinline__ float tanhf_(float x){ return 1.0f - 2.0f/(__expf(2.0f*x)+1.0f); }
__device__ __forceinline__ float softplusf_(float x){
  float ax = fabsf(x);
  return fmaxf(x, 0.0f) + __logf(1.0f + __expf(-ax));
}

// ---- runtime dtype detection from timestamps (positive, 0.25..512) ----
__device__ __forceinline__ bool detect_bf16(const void* ts){
  const unsigned short* p = (const unsigned short*)ts;
  int cnt = 0;
  #pragma unroll
  for (int i = 0; i < 32; ++i){
    unsigned short v = p[2*i];
    int e = (v >> 7) & 0xFF;
    cnt += (((v & 0x8000u) == 0) && e >= 110 && e <= 140) ? 1 : 0;
  }
  return cnt >= 16;
}

__device__ __forceinline__ float lde(const void* p, size_t i, bool bfm){
  return bfm ? bf2f(((const unsigned short*)p)[i]) : ((const float*)p)[i];
}
__device__ __forceinline__ void sto(void* p, size_t i, float v, bool bfm){
  if (bfm) ((unsigned short*)p)[i] = f2bf(v);
  else     ((float*)p)[i] = v;
}

// ============================================================
// Kernel 1: emb_gates[c][j] = b_cell[j] + sum_k emb[c][k]*W[k][j]  (bf16 out)
// ============================================================
__global__ void k_embgates(const void* __restrict__ emb,
                           const void* __restrict__ W,
                           const void* __restrict__ bcell,
                           const void* __restrict__ ts,
                           unsigned short* __restrict__ eg){
  const bool bfm = detect_bf16(ts);
  __shared__ __align__(16) float xs[8][EE];
  const int tid = threadIdx.x;
  const int c0  = blockIdx.y * 8;
  const int j   = blockIdx.x * 512 + tid * 2;

  #pragma unroll
  for (int r = 0; r < 4; ++r){
    int e = tid + 256*r;                 // 0..1023
    int ci = e >> 7, k = e & 127;
    xs[ci][k] = lde(emb, (size_t)(c0+ci)*EE + k, bfm);
  }
  __syncthreads();

  float acc[8][2];
  {
    float b0v = lde(bcell, j, bfm), b1v = lde(bcell, j+1, bfm);
    #pragma unroll
    for (int ci=0; ci<8; ++ci){ acc[ci][0] = b0v; acc[ci][1] = b1v; }
  }
  const unsigned short* W16 = (const unsigned short*)W;
  const float*          W32 = (const float*)W;
  for (int k0 = 0; k0 < EE; k0 += 4){
    float w0[4], w1[4];
    if (bfm){
      #pragma unroll
      for (int kk=0; kk<4; ++kk){
        unsigned wu = *(const unsigned*)&W16[(size_t)(k0+kk)*G7 + j];
        w0[kk] = bf2f((unsigned short)(wu & 0xffff));
        w1[kk] = bf2f((unsigned short)(wu >> 16));
      }
    } else {
      #pragma unroll
      for (int kk=0; kk<4; ++kk){
        float2 wf = *(const float2*)&W32[(size_t)(k0+kk)*G7 + j];
        w0[kk] = wf.x; w1[kk] = wf.y;
      }
    }
    #pragma unroll
    for (int ci=0; ci<8; ++ci){
      float4 x4 = *(const float4*)&xs[ci][k0];
      acc[ci][0] = fmaf(x4.x, w0[0], acc[ci][0]); acc[ci][1] = fmaf(x4.x, w1[0], acc[ci][1]);
      acc[ci][0] = fmaf(x4.y, w0[1], acc[ci][0]); acc[ci][1] = fmaf(x4.y, w1[1], acc[ci][1]);
      acc[ci][0] = fmaf(x4.z, w0[2], acc[ci][0]); acc[ci][1] = fmaf(x4.z, w1[2], acc[ci][1]);
      acc[ci][0] = fmaf(x4.w, w0[3], acc[ci][0]); acc[ci][1] = fmaf(x4.w, w1[3], acc[ci][1]);
    }
  }
  #pragma unroll
  for (int ci=0; ci<8; ++ci){
    unsigned outv = (unsigned)f2bf(acc[ci][0]) | ((unsigned)f2bf(acc[ci][1]) << 16);
    *(unsigned*)&eg[(size_t)(c0+ci)*G7 + j] = outv;
  }
}

// ============================================================
// Kernel 2: WqT[j][k] = W[EE+k][j]  (bf16, 3584 x 512, transposed)
// ============================================================
__global__ void k_wqbf(const void* __restrict__ W,
                       const void* __restrict__ ts,
                       unsigned short* __restrict__ wqt){
  const bool bfm = detect_bf16(ts);
  __shared__ __align__(16) unsigned short tile[64][72];
  const int tid = threadIdx.x;
  const int j0 = blockIdx.x * 64;
  const int k0 = blockIdx.y * 64;
  const int c = tid & 63, r0 = tid >> 6;
  #pragma unroll
  for (int rr = 0; rr < 16; ++rr){
    int r = r0*16 + rr;
    tile[r][c] = f2bf(lde(W, (size_t)(EE + k0 + r)*G7 + (j0 + c), bfm));
  }
  __syncthreads();
  const int jj = tid >> 2, p = tid & 3;
  unsigned short o[16];
  #pragma unroll
  for (int q = 0; q < 16; ++q) o[q] = tile[p*16 + q][jj];
  unsigned short* dst = &wqt[(size_t)(j0+jj)*HH + k0 + p*16];
  *(uint4*)(dst)     = *(uint4*)&o[0];
  *(uint4*)(dst + 8) = *(uint4*)&o[8];
}

// ============================================================
// Kernel 3: persistent cooperative scan.
// grid 64 = 4 batch-groups x 16 i-groups; block 1024 (16 waves).
// Each wave holds one 16-col B tile in regs (bq[16], 64 VGPR).
// Sync group is 16 participants (was 64). Spin is wave-0-only
// (proven protocol shape; avoids 16x coherent spin traffic).
// Output stores after flag release (drain under next spin).
// ============================================================
__launch_bounds__(1024, 1)
__global__ void k_scan(const int* __restrict__ marks,
                       const void* __restrict__ ts,
                       const void* __restrict__ ih,
                       const unsigned short* __restrict__ eg,
                       const unsigned short* __restrict__ wqt,
                       void* __restrict__ out,
                       unsigned int* flags,
                       unsigned long long* dbuf){
  const bool bfm = detect_bf16(ts);
  __shared__ __align__(16) unsigned short hdl[BW][HLDS];   // bf16 h_d, 16 batches x 512
  __shared__ __align__(16) float gl[BW][257];              // MFMA result staging (256 cols + pad)
  __shared__ __align__(16) unsigned short xgl[2][BW][240]; // x_gates double buffer (bf16, 224 used)

  const int tid  = threadIdx.x;
  const int g_i  = blockIdx.x & (NIG-1);
  const int g_b  = blockIdx.x >> 4;
  const int b0   = g_b * BW;
  const int i0   = g_i * II;
  const int lane = tid & 63;
  const int wv   = tid >> 6;

  // ---- B fragments (Wh column slice, bf16) into registers ----
  short8 bq[16];
  {
    int n = lane & 15, q = lane >> 4;
    int coll = wv*16 + n;                         // 0..255 (224..255 pad)
    int cl = (coll < NCOL) ? coll : 0;            // pad cols alias col 0 (output unused)
    int cg = ((cl >> 5) * HH) + i0 + (cl & 31);   // global column = gate*512 + i
    const unsigned short* wb = wqt + (size_t)cg*HH + q*8;
    #pragma unroll
    for (int kk = 0; kk < 16; ++kk)
      bq[kk] = *(const short8*)(wb + kk*32);
  }

  // ---- initial h_d (same for all batches) ----
  {
    int i = (tid & 255) * 2;
    unsigned short h0 = f2bf(tanhf_(lde(ih, i,   bfm)));
    unsigned short h1 = f2bf(tanhf_(lde(ih, i+1, bfm)));
    unsigned v = (unsigned)h0 | ((unsigned)h1 << 16);
    int bb0 = (tid >> 8) * 4;
    #pragma unroll
    for (int b = 0; b < 4; ++b) *(unsigned*)&hdl[bb0 + b][i] = v;
  }

  // ---- per-thread recurrent state (threads 0..511: b=tid>>5, ii=tid&31) ----
  float cd = 0.0f, cbar = 0.0f, dtv = 0.0f;
  if (tid < 512){
    int b = tid >> 5, ii = tid & 31;
    int i = i0 + ii;
    float h0  = tanhf_(lde(ih, i, bfm));
    float cd0 = tanhf_(lde(ih, 512 + i, bfm));
    float cb0 = tanhf_(lde(ih, 1024 + i, bfm));
    float c0v = tanhf_(lde(ih, 1536 + i, bfm));
    float d0  = softplusf_(lde(ih, 2048 + i, bfm));
    float o0  = sigmoidf_(lde(ih, 2560 + i, bfm));
    cd = cd0; cbar = cb0;
    size_t ob = ((size_t)(b0 + b) * TP1) * H6 + i;   // t = 0
    sto(out, ob,        h0,  bfm);
    sto(out, ob +   HH, o0,  bfm);
    sto(out, ob + 2*HH, cb0, bfm);
    sto(out, ob + 3*HH, c0v, bfm);
    sto(out, ob + 4*HH, d0,  bfm);
    sto(out, ob + 5*HH, cd0, bfm);
  }

  // ---- prefetch x_gates for t=0 (eg is internal bf16; copy raw 16B) ----
  if (tid < 512){
    int b = tid >> 5, c = tid & 31;
    if (c < 28){
      int mk = marks[(b0 + b)*TT + 0];
      int g = c >> 2, m4 = c & 3;
      uint4 v = *(const uint4*)&eg[(size_t)mk*G7 + g*HH + i0 + m4*8];
      *(uint4*)&xgl[0][b][c*8] = v;
    }
  }
  __syncthreads();

  const int m_ = lane & 15, q_ = lane >> 4;

  for (int t = 0; t < TT; ++t){
    const int cur = t & 1, nxt = cur ^ 1;

    // (a) prefetch x_gates for t+1 (overlaps the spin)
    if (t < TT-1 && tid < 512){
      int b = tid >> 5, c = tid & 31;
      if (c < 28){
        int mk = marks[(b0 + b)*TT + (t+1)];
        int g = c >> 2, m4 = c & 3;
        uint4 v = *(const uint4*)&eg[(size_t)mk*G7 + g*HH + i0 + m4*8];
        *(uint4*)&xgl[nxt][b][c*8] = v;
      }
    }
    // (a2) dt for this step
    if (tid < 512){
      int b = tid >> 5;
      float t1  = lde(ts, (size_t)(b0 + b)*TT + t, bfm);
      float t0_ = (t > 0) ? lde(ts, (size_t)(b0 + b)*TT + t - 1, bfm) : 0.0f;
      dtv = t1 - t0_;
    }

    // (b) wait for group's h_d(t) (wave 0 spins), then all load into LDS
    if (t > 0){
      if (wv == 0){
        unsigned* fl = &flags[g_b * 64];
        const unsigned target = (unsigned)t;
        for (;;){
          unsigned v = __hip_atomic_load(&fl[lane & 15], __ATOMIC_RELAXED, __HIP_MEMORY_SCOPE_AGENT);
          if (__all((int)(v >= target))) break;
          __builtin_amdgcn_s_sleep(1);
        }
        __threadfence();
      }
      __syncthreads();
      const unsigned long long* src = dbuf + ((size_t)(g_b*2 + cur) * BW) * (HH/4);
      #pragma unroll
      for (int r = 0; r < 2; ++r){
        int idx = tid + 1024*r;          // 0..2047 u64s = 16 x 128
        int bb = idx >> 7, oo = idx & 127;
        unsigned long long v = __hip_atomic_load(&src[(size_t)bb*(HH/4) + oo],
                                                 __ATOMIC_RELAXED, __HIP_MEMORY_SCOPE_AGENT);
        *(unsigned long long*)&hdl[bb][oo*4] = v;
      }
    }
    __syncthreads();   // hdl ready

    // (d) GEMM: G[16 x 256cols] = h(16x512) @ Wh(512x256cols), per-wave 16-col tile
    f32x4 acc = {0.f, 0.f, 0.f, 0.f};
    #pragma unroll
    for (int kk = 0; kk < 16; ++kk){
      short8 a = *(const short8*)&hdl[m_][kk*32 + q_*8];
      acc = __builtin_amdgcn_mfma_f32_16x16x32_bf16(a, bq[kk], acc, 0, 0, 0);
    }
    // (e) C layout: col(N) = lane&15, row(M) = (lane>>4)*4 + reg
    {
      int col  = wv*16 + (lane & 15);
      int rowb = (lane >> 4) * 4;
      #pragma unroll
      for (int r = 0; r < 4; ++r) gl[rowb + r][col] = acc[r];
    }
    __syncthreads();   // gl ready

    // (g) epilogue: gates + state update + publish h; outputs deferred
    float hdt = 0.f, gov = 0.f, cbv = 0.f, cv = 0.f, gdv = 0.f, cdtv = 0.f;
    if (tid < 512){
      int b = tid >> 5, ii = tid & 31;
      float gv[7];
      #pragma unroll
      for (int g = 0; g < 7; ++g)
        gv[g] = gl[b][g*32 + ii] + bf2f(xgl[cur][b][g*32 + ii]);
      float gi  = sigmoidf_(gv[0]);
      float gf  = sigmoidf_(gv[1]);
      float gz  = tanhf_(gv[2]);
      gov       = sigmoidf_(gv[3]);
      float gib = sigmoidf_(gv[4]);
      float gfb = sigmoidf_(gv[5]);
      gdv       = softplusf_(gv[6]);
      cv   = gf*cd + gi*gz;
      cbv  = gfb*cbar + gib*gz;
      float dec = __expf(-gdv * dtv);
      cdtv = cbv + (cv - cbv)*dec;
      hdt  = gov * tanhf_(cdtv);
      cd = cdtv; cbar = cbv;

      // pack 4 consecutive ii's bf16 into u64 via shfl, publish via agent atomics
      unsigned hv = (unsigned)f2bf(hdt);
      unsigned a2 = hv | ((unsigned)__shfl_xor((int)hv, 1) << 16);
      unsigned hi = (unsigned)__shfl_xor((int)a2, 2);
      if ((tid & 3) == 0){
        unsigned long long v64 = (unsigned long long)a2 | ((unsigned long long)hi << 32);
        unsigned long long* dst = dbuf + ((size_t)(g_b*2 + nxt) * BW + b) * (HH/4)
                                       + ((i0 + ii) >> 2);
        __hip_atomic_store(dst, v64, __ATOMIC_RELAXED, __HIP_MEMORY_SCOPE_AGENT);
      }
    }
    __syncthreads();   // drain publishes + protect xgl/gl/hdl reuse
    if (tid == 0){
      __threadfence();
      __hip_atomic_store(&flags[g_b*64 + g_i], (unsigned)(t + 1),
                         __ATOMIC_RELEASE, __HIP_MEMORY_SCOPE_AGENT);
    }
    // (h) output stores AFTER flag release — drain under the next spin
    if (tid < 512){
      int b = tid >> 5, ii = tid & 31;
      size_t ob = ((size_t)(b0 + b) * TP1 + (t+1)) * H6 + i0 + ii;
      sto(out, ob,        hdt,  bfm);
      sto(out, ob +   HH, gov,  bfm);
      sto(out, ob + 2*HH, cbv,  bfm);
      sto(out, ob + 3*HH, cv,   bfm);
      sto(out, ob + 4*HH, gdv,  bfm);
      sto(out, ob + 5*HH, cdtv, bfm);
    }
  }
}

// ============================================================
extern "C" void kernel_launch(void* const* d_in, const int* in_sizes, int n_in,
                              void* d_out, int out_size, void* d_ws, size_t ws_size,
                              hipStream_t stream){
  const int*  marks = (const int*)d_in[0];
  const void* ts    = d_in[1];
  const void* emb   = d_in[2];
  const void* W     = d_in[3];
  const void* bc    = d_in[4];
  const void* ih    = d_in[5];

  unsigned char* ws = (unsigned char*)d_ws;
  unsigned int*       flags = (unsigned int*)ws;                        // 1 KB
  unsigned long long* dbuf  = (unsigned long long*)(ws + 1024);         // 128 KB (4g x 2 x 16KB)
  unsigned short*     eg    = (unsigned short*)(ws + 132096);           // 7,168,000 B
  unsigned short*     wqt   = (unsigned short*)(ws + 132096 + 7168000); // 3,670,016 B
  (void)in_sizes; (void)n_in; (void)out_size;

  if (ws_size < (size_t)(132096 + 7168000 + 3670016)) return;

  hipMemsetAsync(flags, 0, 1024, stream);
  hipLaunchKernelGGL(k_embgates, dim3(7, 125), dim3(256), 0, stream, emb, W, bc, ts, eg);
  hipLaunchKernelGGL(k_wqbf,     dim3(56, 8),  dim3(256), 0, stream, W, ts, wqt);

  void* args[] = { (void*)&marks, (void*)&ts, (void*)&ih, (void*)&eg,
                   (void*)&wqt, (void*)&d_out, (void*)&flags, (void*)&dbuf };
  hipLaunchCooperativeKernel((const void*)k_scan, dim3(64), dim3(1024), args, 0, stream);
}

// Round 3
// 4123.166 us; speedup vs baseline: 2.4514x; 1.0106x over previous
//
#include <hip/hip_runtime.h>
#include <stdint.h>

// ---------------- problem constants ----------------
#define TT    512
#define HH    512
#define EE    128
#define G7    (7*HH)    // 3584
#define H6    (6*HH)    // 3072
#define TP1   (TT+1)    // 513

// ---------------- scan decomposition ----------------
// grid 64 = 4 batch-groups x 16 i-groups. Block = 512 threads (8 waves).
// Each wave owns TWO 16-col MFMA tiles (bq0/bq1, 128 VGPR total for B);
// block covers 7 gates x 32 hidden idx (224 cols of 256).
// XCD pairing: g_b = (bid&7)>>1 puts a batch-group's 16 blocks on 2 XCDs.
#define BW 16
#define II 32
#define NIG 16
#define NCOL 224
#define HLDS 520        // u16 row stride: 1040 B, 16B-aligned rows

typedef float f32x4 __attribute__((ext_vector_type(4)));
typedef short short8 __attribute__((ext_vector_type(8)));

__device__ __forceinline__ float bf2f(unsigned short u){
  union { unsigned u32; float f; } v; v.u32 = ((unsigned)u) << 16; return v.f;
}
__device__ __forceinline__ unsigned short f2bf(float f){
  union { float f; unsigned u; } v; v.f = f;
  unsigned u = v.u;
  u += 0x7FFFu + ((u >> 16) & 1u);   // RNE
  return (unsigned short)(u >> 16);
}
__device__ __forceinline__ float sigmoidf_(float x){ return 1.0f/(1.0f+__expf(-x)); }
__device__ __forceinline__ float tanhf_(float x){ return 1.0f - 2.0f/(__expf(2.0f*x)+1.0f); }
__device__ __forceinline__ float softplusf_(float x){
  float ax = fabsf(x);
  return fmaxf(x, 0.0f) + __logf(1.0f + __expf(-ax));
}

// ---- runtime dtype detection from timestamps (positive, 0.25..512) ----
__device__ __forceinline__ bool detect_bf16(const void* ts){
  const unsigned short* p = (const unsigned short*)ts;
  int cnt = 0;
  #pragma unroll
  for (int i = 0; i < 32; ++i){
    unsigned short v = p[2*i];
    int e = (v >> 7) & 0xFF;
    cnt += (((v & 0x8000u) == 0) && e >= 110 && e <= 140) ? 1 : 0;
  }
  return cnt >= 16;
}

__device__ __forceinline__ float lde(const void* p, size_t i, bool bfm){
  return bfm ? bf2f(((const unsigned short*)p)[i]) : ((const float*)p)[i];
}
__device__ __forceinline__ void sto(void* p, size_t i, float v, bool bfm){
  if (bfm) ((unsigned short*)p)[i] = f2bf(v);
  else     ((float*)p)[i] = v;
}

// ============================================================
// Kernel 1: emb_gates[c][j] = b_cell[j] + sum_k emb[c][k]*W[k][j]  (bf16 out)
// ============================================================
__global__ void k_embgates(const void* __restrict__ emb,
                           const void* __restrict__ W,
                           const void* __restrict__ bcell,
                           const void* __restrict__ ts,
                           unsigned short* __restrict__ eg){
  const bool bfm = detect_bf16(ts);
  __shared__ __align__(16) float xs[8][EE];
  const int tid = threadIdx.x;
  const int c0  = blockIdx.y * 8;
  const int j   = blockIdx.x * 512 + tid * 2;

  #pragma unroll
  for (int r = 0; r < 4; ++r){
    int e = tid + 256*r;                 // 0..1023
    int ci = e >> 7, k = e & 127;
    xs[ci][k] = lde(emb, (size_t)(c0+ci)*EE + k, bfm);
  }
  __syncthreads();

  float acc[8][2];
  {
    float b0v = lde(bcell, j, bfm), b1v = lde(bcell, j+1, bfm);
    #pragma unroll
    for (int ci=0; ci<8; ++ci){ acc[ci][0] = b0v; acc[ci][1] = b1v; }
  }
  const unsigned short* W16 = (const unsigned short*)W;
  const float*          W32 = (const float*)W;
  for (int k0 = 0; k0 < EE; k0 += 4){
    float w0[4], w1[4];
    if (bfm){
      #pragma unroll
      for (int kk=0; kk<4; ++kk){
        unsigned wu = *(const unsigned*)&W16[(size_t)(k0+kk)*G7 + j];
        w0[kk] = bf2f((unsigned short)(wu & 0xffff));
        w1[kk] = bf2f((unsigned short)(wu >> 16));
      }
    } else {
      #pragma unroll
      for (int kk=0; kk<4; ++kk){
        float2 wf = *(const float2*)&W32[(size_t)(k0+kk)*G7 + j];
        w0[kk] = wf.x; w1[kk] = wf.y;
      }
    }
    #pragma unroll
    for (int ci=0; ci<8; ++ci){
      float4 x4 = *(const float4*)&xs[ci][k0];
      acc[ci][0] = fmaf(x4.x, w0[0], acc[ci][0]); acc[ci][1] = fmaf(x4.x, w1[0], acc[ci][1]);
      acc[ci][0] = fmaf(x4.y, w0[1], acc[ci][0]); acc[ci][1] = fmaf(x4.y, w1[1], acc[ci][1]);
      acc[ci][0] = fmaf(x4.z, w0[2], acc[ci][0]); acc[ci][1] = fmaf(x4.z, w1[2], acc[ci][1]);
      acc[ci][0] = fmaf(x4.w, w0[3], acc[ci][0]); acc[ci][1] = fmaf(x4.w, w1[3], acc[ci][1]);
    }
  }
  #pragma unroll
  for (int ci=0; ci<8; ++ci){
    unsigned outv = (unsigned)f2bf(acc[ci][0]) | ((unsigned)f2bf(acc[ci][1]) << 16);
    *(unsigned*)&eg[(size_t)(c0+ci)*G7 + j] = outv;
  }
}

// ============================================================
// Kernel 2: WqT[j][k] = W[EE+k][j]  (bf16, 3584 x 512, transposed)
// ============================================================
__global__ void k_wqbf(const void* __restrict__ W,
                       const void* __restrict__ ts,
                       unsigned short* __restrict__ wqt){
  const bool bfm = detect_bf16(ts);
  __shared__ __align__(16) unsigned short tile[64][72];
  const int tid = threadIdx.x;
  const int j0 = blockIdx.x * 64;
  const int k0 = blockIdx.y * 64;
  const int c = tid & 63, r0 = tid >> 6;
  #pragma unroll
  for (int rr = 0; rr < 16; ++rr){
    int r = r0*16 + rr;
    tile[r][c] = f2bf(lde(W, (size_t)(EE + k0 + r)*G7 + (j0 + c), bfm));
  }
  __syncthreads();
  const int jj = tid >> 2, p = tid & 3;
  unsigned short o[16];
  #pragma unroll
  for (int q = 0; q < 16; ++q) o[q] = tile[p*16 + q][jj];
  unsigned short* dst = &wqt[(size_t)(j0+jj)*HH + k0 + p*16];
  *(uint4*)(dst)     = *(uint4*)&o[0];
  *(uint4*)(dst + 8) = *(uint4*)&o[8];
}

// ============================================================
// Kernel 3: persistent cooperative scan.
// grid 64 = 4 batch-groups x 16 i-groups; block 512 (8 waves).
// Wave0 spins + solo-stages h into LDS -> single barrier (merges
// spin-barrier + stage-barrier). 3 barriers/step total.
// All 512 threads run the epilogue (no idle half).
// ============================================================
__launch_bounds__(512, 2)
__global__ void k_scan(const int* __restrict__ marks,
                       const void* __restrict__ ts,
                       const void* __restrict__ ih,
                       const unsigned short* __restrict__ eg,
                       const unsigned short* __restrict__ wqt,
                       void* __restrict__ out,
                       unsigned int* flags,
                       unsigned long long* dbuf){
  const bool bfm = detect_bf16(ts);
  __shared__ __align__(16) unsigned short hdl[BW][HLDS];   // bf16 h_d, 16 batches x 512
  __shared__ __align__(16) float gl[BW][257];              // MFMA result staging
  __shared__ __align__(16) unsigned short xgl[2][BW][240]; // x_gates double buffer (224 used)

  const int tid  = threadIdx.x;
  const int bid  = blockIdx.x;
  // XCD pairing: blocks with (bid&7) in {2g,2g+1} form batch-group g (2 XCDs/group).
  const int g_b  = (bid & 7) >> 1;
  const int g_i  = ((bid >> 3) << 1) | (bid & 1);
  const int b0   = g_b * BW;
  const int i0   = g_i * II;
  const int lane = tid & 63;
  const int wv   = tid >> 6;
  const int eb   = tid >> 5;     // epilogue batch 0..15
  const int eii  = tid & 31;     // epilogue hidden idx 0..31

  // ---- B fragments: two 16-col tiles per wave, bf16 in registers ----
  short8 bq0[16], bq1[16];
  {
    int n = lane & 15, q = lane >> 4;
    int coll0 = wv*32 + n;                         // tile 0 col
    int coll1 = wv*32 + 16 + n;                    // tile 1 col
    int cl0 = (coll0 < NCOL) ? coll0 : 0;
    int cl1 = (coll1 < NCOL) ? coll1 : 0;
    int cg0 = ((cl0 >> 5) * HH) + i0 + (cl0 & 31);
    int cg1 = ((cl1 >> 5) * HH) + i0 + (cl1 & 31);
    const unsigned short* wb0 = wqt + (size_t)cg0*HH + q*8;
    const unsigned short* wb1 = wqt + (size_t)cg1*HH + q*8;
    #pragma unroll
    for (int kk = 0; kk < 16; ++kk){
      bq0[kk] = *(const short8*)(wb0 + kk*32);
      bq1[kk] = *(const short8*)(wb1 + kk*32);
    }
  }

  // ---- initial h_d (same for all batches) ----
  {
    int i = (tid & 255) * 2;
    unsigned short h0 = f2bf(tanhf_(lde(ih, i,   bfm)));
    unsigned short h1 = f2bf(tanhf_(lde(ih, i+1, bfm)));
    unsigned v = (unsigned)h0 | ((unsigned)h1 << 16);
    int bb0 = (tid >> 8) * 8;
    #pragma unroll
    for (int b = 0; b < 8; ++b) *(unsigned*)&hdl[bb0 + b][i] = v;
  }

  // ---- per-thread recurrent state: all 512 threads (b=eb, ii=eii) ----
  float cd, cbar, tsp = 0.0f;
  {
    int i = i0 + eii;
    float h0  = tanhf_(lde(ih, i, bfm));
    float cd0 = tanhf_(lde(ih, 512 + i, bfm));
    float cb0 = tanhf_(lde(ih, 1024 + i, bfm));
    float c0v = tanhf_(lde(ih, 1536 + i, bfm));
    float d0  = softplusf_(lde(ih, 2048 + i, bfm));
    float o0  = sigmoidf_(lde(ih, 2560 + i, bfm));
    cd = cd0; cbar = cb0;
    size_t ob = ((size_t)(b0 + eb) * TP1) * H6 + i;   // t = 0
    sto(out, ob,        h0,  bfm);
    sto(out, ob +   HH, o0,  bfm);
    sto(out, ob + 2*HH, cb0, bfm);
    sto(out, ob + 3*HH, c0v, bfm);
    sto(out, ob + 4*HH, d0,  bfm);
    sto(out, ob + 5*HH, cd0, bfm);
  }

  // ---- prefetch x_gates for t=0 ----
  if (eii < 28){
    int mk = marks[(b0 + eb)*TT + 0];
    int g = eii >> 2, m4 = eii & 3;
    uint4 v = *(const uint4*)&eg[(size_t)mk*G7 + g*HH + i0 + m4*8];
    *(uint4*)&xgl[0][eb][eii*8] = v;
  }
  __syncthreads();

  const int m_ = lane & 15, q_ = lane >> 4;

  for (int t = 0; t < TT; ++t){
    const int cur = t & 1, nxt = cur ^ 1;

    // (a) prefetch x_gates for t+1 (overlaps the spin)
    if (t < TT-1 && eii < 28){
      int mk = marks[(b0 + eb)*TT + (t+1)];
      int g = eii >> 2, m4 = eii & 3;
      uint4 v = *(const uint4*)&eg[(size_t)mk*G7 + g*HH + i0 + m4*8];
      *(uint4*)&xgl[nxt][eb][eii*8] = v;
    }
    // (a2) dt for this step (ts[t-1] carried in register)
    float dtv;
    {
      float t1 = lde(ts, (size_t)(b0 + eb)*TT + t, bfm);
      dtv = t1 - tsp; tsp = t1;
    }

    // (b) wave0: spin for group's h_d(t), then solo-stage into LDS.
    //     Single barrier covers both (other waves arrive early and wait).
    if (t > 0 && wv == 0){
      {
        unsigned* fl = &flags[g_b * 64];
        const unsigned target = (unsigned)t;
        for (;;){
          unsigned v = __hip_atomic_load(&fl[lane & 15], __ATOMIC_RELAXED, __HIP_MEMORY_SCOPE_AGENT);
          if (__all((int)(v >= target))) break;
          __builtin_amdgcn_s_sleep(1);
        }
        __threadfence();
      }
      const unsigned long long* src = dbuf + ((size_t)(g_b*2 + cur) * BW) * (HH/4);
      #pragma unroll
      for (int half = 0; half < 2; ++half){
        unsigned long long tmp[16];
        #pragma unroll
        for (int r = 0; r < 16; ++r){
          int idx = (half*16 + r)*64 + lane;   // dbuf slice is contiguous 2048 u64
          tmp[r] = __hip_atomic_load(&src[idx], __ATOMIC_RELAXED, __HIP_MEMORY_SCOPE_AGENT);
        }
        #pragma unroll
        for (int r = 0; r < 16; ++r){
          int idx = (half*16 + r)*64 + lane;
          *(unsigned long long*)&hdl[idx >> 7][(idx & 127)*4] = tmp[r];
        }
      }
    }
    __syncthreads();   // hdl ready (barrier #1)

    // (d) GEMM: G[16 x 256cols], each wave two 16-col tiles, shared A fragment
    f32x4 acc0 = {0.f,0.f,0.f,0.f}, acc1 = {0.f,0.f,0.f,0.f};
    #pragma unroll
    for (int kk = 0; kk < 16; ++kk){
      short8 a = *(const short8*)&hdl[m_][kk*32 + q_*8];
      acc0 = __builtin_amdgcn_mfma_f32_16x16x32_bf16(a, bq0[kk], acc0, 0, 0, 0);
      acc1 = __builtin_amdgcn_mfma_f32_16x16x32_bf16(a, bq1[kk], acc1, 0, 0, 0);
    }
    // (e) C layout: col(N) = lane&15, row(M) = (lane>>4)*4 + reg
    {
      int col0 = wv*32 + (lane & 15);
      int rowb = (lane >> 4) * 4;
      #pragma unroll
      for (int r = 0; r < 4; ++r){
        gl[rowb + r][col0]      = acc0[r];
        gl[rowb + r][col0 + 16] = acc1[r];
      }
    }
    __syncthreads();   // gl ready (barrier #2)

    // (g) epilogue: all 512 threads; publish h; outputs deferred past flag
    float hdt, gov, cbv, cv, gdv, cdtv;
    {
      float gv[7];
      #pragma unroll
      for (int g = 0; g < 7; ++g)
        gv[g] = gl[eb][g*32 + eii] + bf2f(xgl[cur][eb][g*32 + eii]);
      float gi  = sigmoidf_(gv[0]);
      float gf  = sigmoidf_(gv[1]);
      float gz  = tanhf_(gv[2]);
      gov       = sigmoidf_(gv[3]);
      float gib = sigmoidf_(gv[4]);
      float gfb = sigmoidf_(gv[5]);
      gdv       = softplusf_(gv[6]);
      cv   = gf*cd + gi*gz;
      cbv  = gfb*cbar + gib*gz;
      float dec = __expf(-gdv * dtv);
      cdtv = cbv + (cv - cbv)*dec;
      hdt  = gov * tanhf_(cdtv);
      cd = cdtv; cbar = cbv;

      // pack 4 consecutive ii's bf16 into u64 via shfl, publish via agent atomics
      unsigned hv = (unsigned)f2bf(hdt);
      unsigned a2 = hv | ((unsigned)__shfl_xor((int)hv, 1) << 16);
      unsigned hi = (unsigned)__shfl_xor((int)a2, 2);
      if ((tid & 3) == 0){
        unsigned long long v64 = (unsigned long long)a2 | ((unsigned long long)hi << 32);
        unsigned long long* dst = dbuf + ((size_t)(g_b*2 + nxt) * BW + eb) * (HH/4)
                                       + ((i0 + eii) >> 2);
        __hip_atomic_store(dst, v64, __ATOMIC_RELAXED, __HIP_MEMORY_SCOPE_AGENT);
      }
    }
    __syncthreads();   // publishes drained; xgl/gl safe to reuse (barrier #3)
    if (tid == 0){
      __threadfence();
      __hip_atomic_store(&flags[g_b*64 + g_i], (unsigned)(t + 1),
                         __ATOMIC_RELEASE, __HIP_MEMORY_SCOPE_AGENT);
    }
    // (h) output stores AFTER flag release — drain under the next spin
    {
      size_t ob = ((size_t)(b0 + eb) * TP1 + (t+1)) * H6 + i0 + eii;
      sto(out, ob,        hdt,  bfm);
      sto(out, ob +   HH, gov,  bfm);
      sto(out, ob + 2*HH, cbv,  bfm);
      sto(out, ob + 3*HH, cv,   bfm);
      sto(out, ob + 4*HH, gdv,  bfm);
      sto(out, ob + 5*HH, cdtv, bfm);
    }
  }
}

// ============================================================
extern "C" void kernel_launch(void* const* d_in, const int* in_sizes, int n_in,
                              void* d_out, int out_size, void* d_ws, size_t ws_size,
                              hipStream_t stream){
  const int*  marks = (const int*)d_in[0];
  const void* ts    = d_in[1];
  const void* emb   = d_in[2];
  const void* W     = d_in[3];
  const void* bc    = d_in[4];
  const void* ih    = d_in[5];

  unsigned char* ws = (unsigned char*)d_ws;
  unsigned int*       flags = (unsigned int*)ws;                        // 1 KB
  unsigned long long* dbuf  = (unsigned long long*)(ws + 1024);         // 128 KB (4g x 2 x 16KB)
  unsigned short*     eg    = (unsigned short*)(ws + 132096);           // 7,168,000 B
  unsigned short*     wqt   = (unsigned short*)(ws + 132096 + 7168000); // 3,670,016 B
  (void)in_sizes; (void)n_in; (void)out_size;

  if (ws_size < (size_t)(132096 + 7168000 + 3670016)) return;

  hipMemsetAsync(flags, 0, 1024, stream);
  hipLaunchKernelGGL(k_embgates, dim3(7, 125), dim3(256), 0, stream, emb, W, bc, ts, eg);
  hipLaunchKernelGGL(k_wqbf,     dim3(56, 8),  dim3(256), 0, stream, W, ts, wqt);

  void* args[] = { (void*)&marks, (void*)&ts, (void*)&ih, (void*)&eg,
                   (void*)&wqt, (void*)&d_out, (void*)&flags, (void*)&dbuf };
  hipLaunchCooperativeKernel((const void*)k_scan, dim3(64), dim3(512), args, 0, stream);
}